// Round 2
// 441.187 us; speedup vs baseline: 1.0332x; 1.0332x over previous
//
#include <hip/hip_runtime.h>

typedef unsigned short u16;
typedef u16 u16x2 __attribute__((ext_vector_type(2)));
typedef u16 u16x4 __attribute__((ext_vector_type(4)));
typedef u16 u16x8 __attribute__((ext_vector_type(8)));
typedef __bf16 bf16x8 __attribute__((ext_vector_type(8)));
typedef float f32x4 __attribute__((ext_vector_type(4)));
typedef float f32x2 __attribute__((ext_vector_type(2)));

#define MFMA16(A, B, C) __builtin_amdgcn_mfma_f32_16x16x32_bf16(A, B, C, 0, 0, 0)

// Constants: B=2, S=2048, E=512, H=8, HD=64
#define SB 2
#define SS 2048
#define SE 512
#define SH 8
#define SHD 64

__device__ __forceinline__ u16 f2b(float f) {
  union { float f; unsigned u; } v;
  v.f = f;
  unsigned r = v.u + 0x7FFFu + ((v.u >> 16) & 1u);  // RNE to bf16
  return (u16)(r >> 16);
}

__device__ __forceinline__ bf16x8 as_bf16x8(u16x8 v) {
  return __builtin_bit_cast(bf16x8, v);
}

// ---------------------------------------------------------------------------
// Prep 1: X [4096,512] f32 -> Xb bf16 (same layout). One-shot conversion so the
// QKV GEMM never re-converts.
// ---------------------------------------------------------------------------
__global__ __launch_bounds__(256)
void convx_kernel(const float* __restrict__ X, u16* __restrict__ Xb)
{
  const int i = (blockIdx.x * 256 + threadIdx.x) * 4;  // exact fit: 2048 blocks
  const float4 v = *(const float4*)&X[i];
  u16x4 o;
  o[0] = f2b(v.x); o[1] = f2b(v.y); o[2] = f2b(v.z); o[3] = f2b(v.w);
  *(u16x4*)&Xb[i] = o;
}

// ---------------------------------------------------------------------------
// Prep 2: W [512,N] f32 -> Wt [N,512] bf16 (transpose + convert, 32x32 tiles).
// ---------------------------------------------------------------------------
__global__ __launch_bounds__(256)
void wtrans_kernel(const float* __restrict__ in, u16* __restrict__ out, int N)
{
  __shared__ float t[32][33];
  const int tid = threadIdx.x;
  const int r = tid >> 3, c4 = (tid & 7) * 4;
  const int k0 = blockIdx.y * 32, n0 = blockIdx.x * 32;
  const float4 v = *(const float4*)&in[(size_t)(k0 + r) * N + n0 + c4];
  t[r][c4 + 0] = v.x; t[r][c4 + 1] = v.y; t[r][c4 + 2] = v.z; t[r][c4 + 3] = v.w;
  __syncthreads();
  u16x4 o;
  o[0] = f2b(t[c4 + 0][r]);
  o[1] = f2b(t[c4 + 1][r]);
  o[2] = f2b(t[c4 + 2][r]);
  o[3] = f2b(t[c4 + 3][r]);
  *(u16x4*)&out[(n0 + r) * 512 + k0 + c4] = o;
}

// ---------------------------------------------------------------------------
// Unified bf16 GEMM: A[M,512] bf16 rm  x  Bt[N,512] bf16 rm  (+ fp32 bias).
// 128x128 tile, BK=32, 256 threads = 4 waves (2x2), each wave 64x64 via 4x4
// 16x16 frags -> 16 MFMA per K-step per wave. All staging is u16x8 vector
// load + ds_write_b128 (no scalar LDS ops, no in-loop conversions).
// MODE 0: QKV epilogue (scatter to Q scaled, K, Vt transposed).
// MODE 1: O-proj epilogue (fp32 Out = acc + bias).
// ---------------------------------------------------------------------------
template <int MODE>
__global__ __launch_bounds__(256, 2)
void gemm_kernel(const u16* __restrict__ A, const u16* __restrict__ Bt,
                 const float* __restrict__ bias,
                 u16* __restrict__ Q, u16* __restrict__ K, u16* __restrict__ Vt,
                 float* __restrict__ Out)
{
  __shared__ __align__(16) u16 As[128 * 40];  // [row][k], stride 40 (pad)
  __shared__ __align__(16) u16 Bs[128 * 40];  // [n][k],   stride 40 (pad)
  const int tid  = threadIdx.x;
  const int lane = tid & 63, wave = tid >> 6, quad = lane >> 4, l16 = lane & 15;
  const int m0 = blockIdx.y * 128, n0 = blockIdx.x * 128;
  const int wr = (wave >> 1) * 64, wc = (wave & 1) * 64;
  const int sr = tid >> 2, sc = (tid & 3) * 8;  // staging: 64 rows x 32 cols / site

  const f32x4 z4 = {0.f, 0.f, 0.f, 0.f};
  f32x4 acc[4][4];
#pragma unroll
  for (int i = 0; i < 4; i++)
#pragma unroll
    for (int j = 0; j < 4; j++) acc[i][j] = z4;

  for (int k0 = 0; k0 < 512; k0 += 32) {
    const u16x8 a0 = *(const u16x8*)&A[(m0 + sr) * 512 + k0 + sc];
    const u16x8 a1 = *(const u16x8*)&A[(m0 + 64 + sr) * 512 + k0 + sc];
    const u16x8 b0 = *(const u16x8*)&Bt[(n0 + sr) * 512 + k0 + sc];
    const u16x8 b1 = *(const u16x8*)&Bt[(n0 + 64 + sr) * 512 + k0 + sc];
    __syncthreads();
    *(u16x8*)&As[sr * 40 + sc]        = a0;
    *(u16x8*)&As[(64 + sr) * 40 + sc] = a1;
    *(u16x8*)&Bs[sr * 40 + sc]        = b0;
    *(u16x8*)&Bs[(64 + sr) * 40 + sc] = b1;
    __syncthreads();
    bf16x8 af[4], bf[4];
#pragma unroll
    for (int i = 0; i < 4; i++) {
      af[i] = as_bf16x8(*(const u16x8*)&As[(wr + i * 16 + l16) * 40 + quad * 8]);
      bf[i] = as_bf16x8(*(const u16x8*)&Bs[(wc + i * 16 + l16) * 40 + quad * 8]);
    }
#pragma unroll
    for (int i = 0; i < 4; i++)
#pragma unroll
      for (int j = 0; j < 4; j++) acc[i][j] = MFMA16(af[i], bf[j], acc[i][j]);
  }

#pragma unroll
  for (int tm = 0; tm < 4; tm++) {
#pragma unroll
    for (int tn = 0; tn < 4; tn++) {
#pragma unroll
      for (int r = 0; r < 4; r++) {
        const int gm = m0 + wr + tm * 16 + quad * 4 + r;  // row in [0,M)
        const int gn = n0 + wc + tn * 16 + l16;           // col in [0,N)
        const float v = acc[tm][tn][r] + bias[gn];
        if (MODE == 0) {
          // scatter into Q (scaled 1/sqrt(64)), K, Vt (transposed)
          const int bb = gm >> 11, s = gm & 2047;
          const int hh = gn / 192, j = gn - hh * 192;
          const int bh = bb * SH + hh;
          if (j < 64)
            Q[(bh * SS + s) * SHD + j] = f2b(v * 0.125f);
          else if (j < 128)
            K[(bh * SS + s) * SHD + (j - 64)] = f2b(v);
          else
            Vt[(bh * SHD + (j - 128)) * SS + s] = f2b(v);
        } else {
          Out[gm * 512 + gn] = v;
        }
      }
    }
  }
}

// ---------------------------------------------------------------------------
// Fused attention: UNCHANGED (control variable).
// Per block = one (b,h), 16 query rows, all 2048 keys. 512 threads = 8 waves;
// wave w owns key columns [w*256, w*256+256).
// ---------------------------------------------------------------------------
__global__ __launch_bounds__(512, 2)
void attn_kernel(const u16* __restrict__ Q, const u16* __restrict__ K,
                 const u16* __restrict__ Vt, u16* __restrict__ values,
                 float* __restrict__ attn)
{
  __shared__ __align__(16) u16 p_lds[8 * 16 * 264];  // 67584 B, stride 264 (pad 8)
  __shared__ float redmax[8][16];
  __shared__ float redsum[8][16];

  const int tid  = threadIdx.x;
  const int lane = tid & 63, wave = tid >> 6, quad = lane >> 4, l16 = lane & 15;
  const int q0 = blockIdx.x * 16;
  const int h = blockIdx.y, b = blockIdx.z, bh = b * SH + h;

  const u16* Qb = Q + bh * SS * SHD;
  const u16* Kb = K + bh * SS * SHD;
  const u16* Vb = Vt + bh * SHD * SS;

  const bf16x8 aq0 = as_bf16x8(*(const u16x8*)&Qb[(q0 + l16) * SHD + quad * 8]);
  const bf16x8 aq1 = as_bf16x8(*(const u16x8*)&Qb[(q0 + l16) * SHD + 32 + quad * 8]);

  // ---- scores: 16 tiles of 16x16 per wave ----
  f32x4 acc[16];
#pragma unroll
  for (int ct = 0; ct < 16; ct++) {
    const int kb = wave * 256 + ct * 16;
    bf16x8 bk0 = as_bf16x8(*(const u16x8*)&Kb[(kb + l16) * SHD + quad * 8]);
    bf16x8 bk1 = as_bf16x8(*(const u16x8*)&Kb[(kb + l16) * SHD + 32 + quad * 8]);
    f32x4 c = {0.f, 0.f, 0.f, 0.f};
    c = MFMA16(aq0, bk0, c);
    c = MFMA16(aq1, bk1, c);
    acc[ct] = c;
  }

  // ---- row max ----
  float mx[4];
#pragma unroll
  for (int r = 0; r < 4; r++) mx[r] = acc[0][r];
#pragma unroll
  for (int ct = 1; ct < 16; ct++)
#pragma unroll
    for (int r = 0; r < 4; r++) mx[r] = fmaxf(mx[r], acc[ct][r]);
#pragma unroll
  for (int off = 1; off < 16; off <<= 1)
#pragma unroll
    for (int r = 0; r < 4; r++) mx[r] = fmaxf(mx[r], __shfl_xor(mx[r], off));
  if (l16 == 0) {
#pragma unroll
    for (int r = 0; r < 4; r++) redmax[wave][quad * 4 + r] = mx[r];
  }
  __syncthreads();
  float gm[4];
#pragma unroll
  for (int r = 0; r < 4; r++) {
    float m = redmax[0][quad * 4 + r];
#pragma unroll
    for (int w = 1; w < 8; w++) m = fmaxf(m, redmax[w][quad * 4 + r]);
    gm[r] = m;
  }

  // ---- exp + row sum ----
  float ls[4] = {0.f, 0.f, 0.f, 0.f};
#pragma unroll
  for (int ct = 0; ct < 16; ct++)
#pragma unroll
    for (int r = 0; r < 4; r++) {
      const float p = __expf(acc[ct][r] - gm[r]);
      acc[ct][r] = p;
      ls[r] += p;
    }
#pragma unroll
  for (int off = 1; off < 16; off <<= 1)
#pragma unroll
    for (int r = 0; r < 4; r++) ls[r] += __shfl_xor(ls[r], off);
  if (l16 == 0) {
#pragma unroll
    for (int r = 0; r < 4; r++) redsum[wave][quad * 4 + r] = ls[r];
  }
  __syncthreads();
  float inv[4];
#pragma unroll
  for (int r = 0; r < 4; r++) {
    float s = redsum[0][quad * 4 + r];
#pragma unroll
    for (int w = 1; w < 8; w++) s += redsum[w][quad * 4 + r];
    inv[r] = 1.f / s;
  }

  // ---- normalize: fp32 P to d_out, bf16 P to LDS ----
  float* attn_b = attn + (bh * SS + q0) * SS;
#pragma unroll
  for (int ct = 0; ct < 16; ct++) {
    const int col = wave * 256 + ct * 16 + l16;
#pragma unroll
    for (int r = 0; r < 4; r++) {
      const float p = acc[ct][r] * inv[r];
      attn_b[(quad * 4 + r) * SS + col] = p;
      p_lds[(wave * 16 + quad * 4 + r) * 264 + ct * 16 + l16] = f2b(p);
    }
  }

  // ---- PV: each wave contracts its own 256 columns ----
  f32x4 oacc[4];
#pragma unroll
  for (int nt = 0; nt < 4; nt++) oacc[nt] = (f32x4){0.f, 0.f, 0.f, 0.f};
#pragma unroll
  for (int kc = 0; kc < 8; kc++) {
    bf16x8 pa = as_bf16x8(*(const u16x8*)&p_lds[(wave * 16 + l16) * 264 + kc * 32 + quad * 8]);
    const int sb = wave * 256 + kc * 32 + quad * 8;
#pragma unroll
    for (int nt = 0; nt < 4; nt++) {
      bf16x8 vb = as_bf16x8(*(const u16x8*)&Vb[(nt * 16 + l16) * SS + sb]);
      oacc[nt] = MFMA16(pa, vb, oacc[nt]);
    }
  }

  // ---- reduce 8 wave-partials through (reused) LDS ----
  __syncthreads();
  float* opart = (float*)p_lds;  // [8][16][64] f32 = 32 KB
#pragma unroll
  for (int nt = 0; nt < 4; nt++)
#pragma unroll
    for (int r = 0; r < 4; r++)
      opart[(wave * 16 + quad * 4 + r) * 64 + nt * 16 + l16] = oacc[nt][r];
  __syncthreads();

  const int q = tid >> 5, d0 = (tid & 31) * 2;
  f32x2 s2 = {0.f, 0.f};
#pragma unroll
  for (int w = 0; w < 8; w++) s2 += *(const f32x2*)&opart[(w * 16 + q) * 64 + d0];
  u16x2 o2;
  o2[0] = f2b(s2[0]);
  o2[1] = f2b(s2[1]);
  *(u16x2*)&values[((b * SS + q0 + q) * SH + h) * SHD + d0] = o2;
}

// ---------------------------------------------------------------------------
// Workspace budget: EXACTLY 16 MiB (= round-0 verified footprint).
//   ws: Q(4MB) K(4MB) Vt(4MB) values(4MB; Xb aliases it)
//   WqkvT: staged in d_out's attn region (dead until attn_kernel overwrites;
//          consumed by qkv gemm which finishes first — stream-serialized).
//   WoT:   aliases the Q region; produced AFTER attn (Q dead), read by oproj.
// ---------------------------------------------------------------------------
extern "C" void kernel_launch(void* const* d_in, const int* in_sizes, int n_in,
                              void* d_out, int out_size, void* d_ws, size_t ws_size,
                              hipStream_t stream) {
  const float* X    = (const float*)d_in[0];
  const float* Wqkv = (const float*)d_in[1];
  const float* bqkv = (const float*)d_in[2];
  const float* Wo   = (const float*)d_in[3];
  const float* bo   = (const float*)d_in[4];

  float* o_out    = (float*)d_out;                       // [2,2048,512]
  float* attn_out = o_out + SB * SS * SE;                // [2,8,2048,2048]

  const size_t QKV_ELEMS = (size_t)SB * SH * SS * SHD;   // 2,097,152 per tensor
  u16* Q      = (u16*)d_ws;
  u16* K      = Q + QKV_ELEMS;
  u16* Vt     = K + QKV_ELEMS;
  u16* values = Vt + QKV_ELEMS;
  u16* Xb     = values;               // dead before attn writes values
  u16* WqkvT  = (u16*)attn_out;       // dead until attn writes attn_out
  u16* WoT    = Q;                    // Q dead after attn; WoT made post-attn

  // Prep: one-shot bf16 conversion / transposition of QKV GEMM operands
  convx_kernel<<<dim3(2048), 256, 0, stream>>>(X, Xb);
  wtrans_kernel<<<dim3(48, 16), 256, 0, stream>>>(Wqkv, WqkvT, 1536);

  // QKV projection: M=4096 (32 m-blocks), N=1536 (12 n-blocks)
  gemm_kernel<0><<<dim3(12, 32), 256, 0, stream>>>(Xb, WqkvT, bqkv, Q, K, Vt, nullptr);
  // Attention: 128 row-blocks x 8 heads x 2 batches (UNCHANGED)
  attn_kernel<<<dim3(128, 8, 2), 512, 0, stream>>>(Q, K, Vt, values, attn_out);
  // Wo transpose into (now-dead) Q region, then O projection
  wtrans_kernel<<<dim3(16, 16), 256, 0, stream>>>(Wo, WoT, 512);
  gemm_kernel<1><<<dim3(4, 32), 256, 0, stream>>>(values, WoT, bo,
                                                  nullptr, nullptr, nullptr, o_out);
}